// Round 9
// baseline (179.714 us; speedup 1.0000x reference)
//
#include <hip/hip_runtime.h>

#define INF_F (__builtin_inff())
#define PMAX 512
#define G1 1024         // chunks == blocks for count/scatter passes
#define BT 512          // threads for k1/k4
#define NPART 256       // nodes per partition (partition = node >> 8)
#define MARKER 0xFFFFFFFFu

// ---------------- common helpers ----------------

__device__ __forceinline__ unsigned int enc_f(float f) {
    unsigned int u = __float_as_uint(f);
    return (u & 0x80000000u) ? ~u : (u | 0x80000000u);
}
__device__ __forceinline__ float dec_f(unsigned int u) {
    unsigned int b = (u & 0x80000000u) ? (u & 0x7FFFFFFFu) : ~u;
    return __uint_as_float(b);
}
__device__ __forceinline__ float inv_clean(float x) {
    float r = 1.0f / x;
    if (isnan(r) || r == INF_F) r = 1.0f;
    return r;
}
__device__ __forceinline__ float edge_final(float ev, float c, float lw, float lb) {
    float ec = (isnan(ev) || ev == INF_F) ? 1.0f : ev;
    float out = ec * lw + lb + c * ec;
    if (out == INF_F) out = 1.0f;
    return out;
}
__device__ __forceinline__ float dot16_bias(const float* __restrict__ edge_attr,
                                            const float* __restrict__ lin_e_w,
                                            const float* __restrict__ lin_e_b, int e) {
    const float4* ea = reinterpret_cast<const float4*>(edge_attr) + (size_t)e * 4;
    const float4* w4 = reinterpret_cast<const float4*>(lin_e_w);
    float4 a0 = ea[0], a1 = ea[1], a2 = ea[2], a3 = ea[3];
    float4 w0 = w4[0], w1 = w4[1], w2 = w4[2], w3 = w4[3];
    return a0.x * w0.x + a0.y * w0.y + a0.z * w0.z + a0.w * w0.w
         + a1.x * w1.x + a1.y * w1.y + a1.z * w1.z + a1.w * w1.w
         + a2.x * w2.x + a2.y * w2.y + a2.z * w2.z + a2.w * w2.w
         + a3.x * w3.x + a3.y * w3.y + a3.z * w3.z + a3.w * w3.w
         + lin_e_b[0];
}

// ---------------- sort path ----------------

// K1 (coalesced): 4 lanes per edge. Each quad loads the edge's 64B of
// edge_attr CONTIGUOUSLY (wave load = 1KB dense), reduces the dot product
// with 2 shfl_xor, compacts ev to lanes 0..15 for dense stores; lanes 0..15
// do the src/dst loads and LDS histogram atomics.
__global__ void __launch_bounds__(BT)
k1_ev_count(const float* __restrict__ edge_attr,
            const int* __restrict__ src, const int* __restrict__ dst,
            const float* __restrict__ lin_e_w, const float* __restrict__ lin_e_b,
            float* __restrict__ ev_out, unsigned int* __restrict__ gh,
            int E, int P, int CE) {
    __shared__ unsigned int hist[PMAX];
    const int t = threadIdx.x, b = blockIdx.x;
    const int lane = t & 63;
    const int wv = t >> 6;               // wave id within block (8 waves)
    for (int p = t; p < P; p += BT) hist[p] = 0u;
    __syncthreads();

    const float4* attr4 = reinterpret_cast<const float4*>(edge_attr);
    const float4  wc    = reinterpret_cast<const float4*>(lin_e_w)[t & 3];
    const float   bias  = lin_e_b[0];

    const int start = b * CE, end = min(E, start + CE);
    const int EPB = BT / 4;              // 128 edges per block-iteration

    for (int base = start; base < end; base += EPB) {
        int e = base + (t >> 2);         // quad-global edge index
        float4 a = make_float4(0.f, 0.f, 0.f, 0.f);
        if (e < end) a = attr4[(size_t)e * 4 + (t & 3)];
        float partial = a.x * wc.x + a.y * wc.y + a.z * wc.z + a.w * wc.w;
        partial += __shfl_xor(partial, 1);
        partial += __shfl_xor(partial, 2);
        // compact: lane j (<16) takes the dot held at lane 4j
        float evc = __shfl(partial, (lane & 15) * 4);
        if (lane < 16) {
            int e16 = base + wv * 16 + lane;
            if (e16 < end) {
                ev_out[e16] = evc + bias;
                unsigned int s = (unsigned int)src[e16];
                unsigned int d = (unsigned int)dst[e16];
                atomicAdd(&hist[s >> 8], 1u);
                atomicAdd(&hist[d >> 8], 1u);
            }
        }
    }
    __syncthreads();
    for (int p = t; p < P; p += BT) gh[(size_t)b * P + p] = hist[p];
}

// K2: per-partition exclusive scan of PADDED block counts (rounded up to 8
// records = one 64B line), in place; padded total -> ptotal[p].
__global__ void __launch_bounds__(256)
k2_scan_cols(unsigned int* __restrict__ gh, unsigned int* __restrict__ ptotal, int P) {
    const int VPT = G1 / 256;
    int p = blockIdx.x, t = threadIdx.x;
    unsigned int v[VPT], s = 0u;
    #pragma unroll
    for (int i = 0; i < VPT; ++i) {
        v[i] = (gh[(size_t)(t * VPT + i) * P + p] + 7u) & ~7u;
        s += v[i];
    }
    __shared__ unsigned int sc[256];
    sc[t] = s;
    __syncthreads();
    for (int off = 1; off < 256; off <<= 1) {
        unsigned int x = (t >= off) ? sc[t - off] : 0u;
        __syncthreads();
        sc[t] += x;
        __syncthreads();
    }
    unsigned int run = sc[t] - s;   // exclusive prefix (padded units)
    #pragma unroll
    for (int i = 0; i < VPT; ++i) {
        gh[(size_t)(t * VPT + i) * P + p] = run;
        run += v[i];
    }
    if (t == 255) ptotal[p] = run;
}

// K3: exclusive scan across partitions -> pbase (all multiples of 8 records).
__global__ void k3_scan_part(const unsigned int* __restrict__ ptotal,
                             unsigned int* __restrict__ pbase, int P) {
    int t = threadIdx.x;
    unsigned int u0 = (2 * t < P) ? ptotal[2 * t] : 0u;
    unsigned int u1 = (2 * t + 1 < P) ? ptotal[2 * t + 1] : 0u;
    unsigned int s = u0 + u1;
    __shared__ unsigned int sc[256];
    sc[t] = s;
    __syncthreads();
    for (int off = 1; off < 256; off <<= 1) {
        unsigned int x = (t >= off) ? sc[t - off] : 0u;
        __syncthreads();
        sc[t] += x;
        __syncthreads();
    }
    unsigned int excl = sc[t] - s;
    if (2 * t < P) pbase[2 * t] = excl;
    if (2 * t + 1 < P) pbase[2 * t + 1] = excl + u0;
}

// K4: scatter packed records to exact positions using LDS cursors; every
// (block,partition) region is 64B-line-aligned and exclusively owned.
// Tail slots (<8) are filled with MARKER records.
__global__ void __launch_bounds__(BT)
k4_scatter(const int* __restrict__ src, const int* __restrict__ dst,
           const float* __restrict__ ev_in,
           const unsigned int* __restrict__ gh, const unsigned int* __restrict__ pbase,
           const unsigned int* __restrict__ ptotal,
           uint2* __restrict__ rec, int E, int P, int CE) {
    __shared__ unsigned int cur[PMAX];
    int t = threadIdx.x, b = blockIdx.x;
    for (int p = t; p < P; p += BT) cur[p] = pbase[p] + gh[(size_t)b * P + p];
    __syncthreads();
    int start = b * CE, end = min(E, start + CE);
    for (int e = start + t; e < end; e += BT) {
        float ev = ev_in[e];
        unsigned int ebits = __float_as_uint(ev);
        unsigned int s = (unsigned int)src[e], d = (unsigned int)dst[e];
        unsigned int pos = atomicAdd(&cur[d >> 8], 1u);
        rec[pos] = make_uint2(ebits, d & 255u);
        pos = atomicAdd(&cur[s >> 8], 1u);
        rec[pos] = make_uint2(ebits, s & 255u);
    }
    __syncthreads();
    for (int p = t; p < P; p += BT) {
        unsigned int rend = pbase[p] +
            ((b + 1 < G1) ? gh[(size_t)(b + 1) * P + p] : ptotal[p]);
        for (unsigned int q = cur[p]; q < rend; ++q)
            rec[q] = make_uint2(0u, MARKER);
    }
}

// K5: per-partition reduce. Contiguous coalesced uint4 sweep of the
// partition's record range (order-independent; markers skipped). 1024 threads.
__global__ void __launch_bounds__(1024)
k5_reduce(const uint2* __restrict__ rec,
          const unsigned int* __restrict__ pbase, const unsigned int* __restrict__ ptotal,
          const float* __restrict__ aggr2_w, const float* __restrict__ aggr2_b,
          float* __restrict__ nodeC, int N) {
    __shared__ float ssum[NPART];
    __shared__ unsigned int scnt[NPART], smax[NPART], smin[NPART];
    int p = blockIdx.x, t = threadIdx.x;
    if (t < NPART) { ssum[t] = 0.0f; scnt[t] = 0u; smax[t] = 0u; smin[t] = 0xFFFFFFFFu; }
    __syncthreads();
    unsigned int pb = pbase[p], tot = ptotal[p];
    const uint4* r4 = reinterpret_cast<const uint4*>(rec + pb);
    unsigned int n4 = tot >> 1;
    for (unsigned int i = t; i < n4; i += 1024) {
        uint4 q = r4[i];
        if (q.y != MARKER) {
            float v = __uint_as_float(q.x);
            unsigned int eu = enc_f(v);
            atomicAdd(&ssum[q.y], v);
            atomicAdd(&scnt[q.y], 1u);
            atomicMax(&smax[q.y], eu);
            atomicMin(&smin[q.y], eu);
        }
        if (q.w != MARKER) {
            float v = __uint_as_float(q.z);
            unsigned int eu = enc_f(v);
            atomicAdd(&ssum[q.w], v);
            atomicAdd(&scnt[q.w], 1u);
            atomicMax(&smax[q.w], eu);
            atomicMin(&smin[q.w], eu);
        }
    }
    __syncthreads();
    int node = p * NPART + t;
    if (t < NPART && node < N) {
        unsigned int c = scnt[t];
        float sum = ssum[t];
        float mxv = (c > 0u) ? dec_f(smax[t]) : 0.0f;
        float mnv = (c > 0u) ? dec_f(smin[t]) : 0.0f;
        float mean = sum / fmaxf((float)c, 1.0f);
        float4 w = *reinterpret_cast<const float4*>(aggr2_w);
        nodeC[node] = w.x * inv_clean(mxv) + w.y * inv_clean(mean)
                    + w.z * inv_clean(mnv) + w.w * inv_clean(sum) + aggr2_b[0];
    }
}

// K6: final edge pass. ev lives in d_out; in-place elementwise rewrite.
__global__ void __launch_bounds__(256)
edge_out(float* __restrict__ evout, const int* __restrict__ dst,
         const float* __restrict__ nodeC,
         const float* __restrict__ lin_l_w, const float* __restrict__ lin_l_b,
         int E) {
    int i = blockIdx.x * blockDim.x + threadIdx.x;
    int base = i * 4;
    float lw = lin_l_w[0], lb = lin_l_b[0];
    if (base + 3 < E) {
        float4 ev = *reinterpret_cast<const float4*>(evout + base);
        int4 d = *reinterpret_cast<const int4*>(dst + base);
        float4 o;
        o.x = edge_final(ev.x, nodeC[d.x], lw, lb);
        o.y = edge_final(ev.y, nodeC[d.y], lw, lb);
        o.z = edge_final(ev.z, nodeC[d.z], lw, lb);
        o.w = edge_final(ev.w, nodeC[d.w], lw, lb);
        *reinterpret_cast<float4*>(evout + base) = o;
    } else {
        for (int e = base; e < E; ++e)
            evout[e] = edge_final(evout[e], nodeC[dst[e]], lw, lb);
    }
}

// ---------------- fallback (R2 atomic path, known-good) ----------------

__global__ void init_nodes_fb(unsigned long long* __restrict__ sc,
                              unsigned int* __restrict__ mx,
                              unsigned int* __restrict__ mn, int total) {
    int i = blockIdx.x * blockDim.x + threadIdx.x;
    if (i < total) { sc[i] = 0ull; mx[i] = 0u; mn[i] = 0xFFFFFFFFu; }
}

__global__ void __launch_bounds__(256)
edge_scatter_fb(const float* __restrict__ edge_attr,
                const int* __restrict__ src, const int* __restrict__ dst,
                const float* __restrict__ lin_e_w, const float* __restrict__ lin_e_b,
                float* __restrict__ ev_out,
                unsigned long long* __restrict__ sc,
                unsigned int* __restrict__ mx, unsigned int* __restrict__ mn,
                int E, int N, int repMask) {
    int e = blockIdx.x * blockDim.x + threadIdx.x;
    if (e >= E) return;
    float ev = dot16_bias(edge_attr, lin_e_w, lin_e_b, e);
    ev_out[e] = ev;
    unsigned long long packed =
        (1ull << 52) | (unsigned long long)((ev + 32.0f) * 1048576.0f);
    unsigned int u = enc_f(ev);
    int base = (blockIdx.x & repMask) * N;
    int s = src[e] + base, d = dst[e] + base;
    atomicAdd(&sc[d], packed);
    atomicAdd(&sc[s], packed);
    atomicMax(&mx[d], u);
    atomicMax(&mx[s], u);
    atomicMin(&mn[d], u);
    atomicMin(&mn[s], u);
}

__global__ void node_combine_fb(const unsigned long long* __restrict__ sc,
                                const unsigned int* __restrict__ mx,
                                const unsigned int* __restrict__ mn,
                                const float* __restrict__ aggr2_w,
                                const float* __restrict__ aggr2_b,
                                float* __restrict__ nodeC, int n, int R) {
    int v = blockIdx.x * blockDim.x + threadIdx.x;
    if (v >= n) return;
    unsigned long long acc = 0ull;
    unsigned int M = 0u, m = 0xFFFFFFFFu;
    for (int r = 0; r < R; ++r) {
        acc += sc[(size_t)r * n + v];
        M = max(M, mx[(size_t)r * n + v]);
        m = min(m, mn[(size_t)r * n + v]);
    }
    unsigned long long icnt = acc >> 52;
    float cnt = (float)icnt;
    double sumfix = (double)(acc & ((1ull << 52) - 1ull));
    float sum = (float)(sumfix * (1.0 / 1048576.0) - 32.0 * (double)icnt);
    float mxv, mnv;
    if (icnt > 0) { mxv = dec_f(M); mnv = dec_f(m); }
    else          { mxv = 0.0f;     mnv = 0.0f; }
    float mean = sum / fmaxf(cnt, 1.0f);
    float4 w = *reinterpret_cast<const float4*>(aggr2_w);
    nodeC[v] = w.x * inv_clean(mxv) + w.y * inv_clean(mean)
             + w.z * inv_clean(mnv) + w.w * inv_clean(sum) + aggr2_b[0];
}

static inline size_t align64(size_t x) { return (x + 63) & ~(size_t)63; }

extern "C" void kernel_launch(void* const* d_in, const int* in_sizes, int n_in,
                              void* d_out, int out_size, void* d_ws, size_t ws_size,
                              hipStream_t stream) {
    const int N = in_sizes[0] / 8;   // x: [N,8] (x otherwise unused)
    const int E = in_sizes[1] / 2;   // adjs: [2,E]

    const int*   adjs      = (const int*)d_in[1];
    const int*   src       = adjs;
    const int*   dst       = adjs + E;
    const float* edge_attr = (const float*)d_in[2];
    const float* lin_e_w   = (const float*)d_in[3];
    const float* lin_e_b   = (const float*)d_in[4];
    const float* aggr2_w   = (const float*)d_in[5];
    const float* aggr2_b   = (const float*)d_in[6];
    const float* lin_l_w   = (const float*)d_in[7];
    const float* lin_l_b   = (const float*)d_in[8];
    float* out = (float*)d_out;      // also holds ev between k1 and k6

    char* ws = (char*)d_ws;

    const int P = (N + NPART - 1) / NPART;
    const int CE = (E + G1 - 1) / G1;

    // sort-path workspace: gh + ptotal + pbase + rec (padded) + nodeC
    size_t max_rec = (size_t)2 * E + (size_t)G1 * P * 8;   // worst-case padding
    size_t off_gh = 0;
    size_t off_pt = align64(off_gh + (size_t)G1 * P * 4);
    size_t off_pb = align64(off_pt + (size_t)PMAX * 4);
    size_t off_rc = align64(off_pb + (size_t)PMAX * 4);
    size_t off_nc = align64(off_rc + max_rec * 8);
    size_t need_sort = off_nc + (size_t)N * 4;

    if (P <= PMAX && ws_size >= need_sort) {
        unsigned int* gh     = (unsigned int*)(ws + off_gh);
        unsigned int* ptotal = (unsigned int*)(ws + off_pt);
        unsigned int* pbase  = (unsigned int*)(ws + off_pb);
        uint2*        rec    = (uint2*)(ws + off_rc);
        float*        nodeC  = (float*)(ws + off_nc);

        hipLaunchKernelGGL(k1_ev_count, dim3(G1), dim3(BT), 0, stream,
                           edge_attr, src, dst, lin_e_w, lin_e_b, out, gh, E, P, CE);
        hipLaunchKernelGGL(k2_scan_cols, dim3(P), dim3(256), 0, stream, gh, ptotal, P);
        hipLaunchKernelGGL(k3_scan_part, dim3(1), dim3(256), 0, stream, ptotal, pbase, P);
        hipLaunchKernelGGL(k4_scatter, dim3(G1), dim3(BT), 0, stream,
                           src, dst, out, gh, pbase, ptotal, rec, E, P, CE);
        hipLaunchKernelGGL(k5_reduce, dim3(P), dim3(1024), 0, stream,
                           rec, pbase, ptotal, aggr2_w, aggr2_b, nodeC, N);
        int nt = (E + 3) / 4;
        hipLaunchKernelGGL(edge_out, dim3((nt + 255) / 256), dim3(256), 0, stream,
                           out, dst, nodeC, lin_l_w, lin_l_b, E);
    } else {
        // R2 atomic fallback: ev in d_out; ws holds R*N accumulators + nodeC.
        int R = 8;
        while (R > 1 && (size_t)R * N * 16 + (size_t)N * 4 > ws_size) R >>= 1;
        unsigned long long* sc    = (unsigned long long*)ws;
        unsigned int*       mx    = (unsigned int*)(sc + (size_t)R * N);
        unsigned int*       mn    = mx + (size_t)R * N;
        float*              nodeC = (float*)(mn + (size_t)R * N);

        int totalRN = R * N;
        hipLaunchKernelGGL(init_nodes_fb, dim3((totalRN + 255) / 256), dim3(256), 0, stream,
                           sc, mx, mn, totalRN);
        hipLaunchKernelGGL(edge_scatter_fb, dim3((E + 255) / 256), dim3(256), 0, stream,
                           edge_attr, src, dst, lin_e_w, lin_e_b,
                           out, sc, mx, mn, E, N, R - 1);
        hipLaunchKernelGGL(node_combine_fb, dim3((N + 255) / 256), dim3(256), 0, stream,
                           sc, mx, mn, aggr2_w, aggr2_b, nodeC, N, R);
        int nt = (E + 3) / 4;
        hipLaunchKernelGGL(edge_out, dim3((nt + 255) / 256), dim3(256), 0, stream,
                           out, dst, nodeC, lin_l_w, lin_l_b, E);
    }
}

// Round 11
// 167.090 us; speedup vs baseline: 1.0756x; 1.0756x over previous
//
#include <hip/hip_runtime.h>

#define INF_F (__builtin_inff())
#define PMAX 512
#define G1 1024         // chunks == blocks for count/scatter passes
#define BT 512          // threads for k1
#define BT4 1024        // threads for k4_staged
#define NPART 256       // nodes per partition (partition = node >> 8)
#define MARKER 0xFFFFFFFFu
#define LREC 9856       // per-block LDS record capacity (uint2)

// ---------------- common helpers ----------------

__device__ __forceinline__ unsigned int enc_f(float f) {
    unsigned int u = __float_as_uint(f);
    return (u & 0x80000000u) ? ~u : (u | 0x80000000u);
}
__device__ __forceinline__ float dec_f(unsigned int u) {
    unsigned int b = (u & 0x80000000u) ? (u & 0x7FFFFFFFu) : ~u;
    return __uint_as_float(b);
}
__device__ __forceinline__ float inv_clean(float x) {
    float r = 1.0f / x;
    if (isnan(r) || r == INF_F) r = 1.0f;
    return r;
}
__device__ __forceinline__ float edge_final(float ev, float c, float lw, float lb) {
    float ec = (isnan(ev) || ev == INF_F) ? 1.0f : ev;
    float out = ec * lw + lb + c * ec;
    if (out == INF_F) out = 1.0f;
    return out;
}
__device__ __forceinline__ float dot16_bias(const float* __restrict__ edge_attr,
                                            const float* __restrict__ lin_e_w,
                                            const float* __restrict__ lin_e_b, int e) {
    const float4* ea = reinterpret_cast<const float4*>(edge_attr) + (size_t)e * 4;
    const float4* w4 = reinterpret_cast<const float4*>(lin_e_w);
    float4 a0 = ea[0], a1 = ea[1], a2 = ea[2], a3 = ea[3];
    float4 w0 = w4[0], w1 = w4[1], w2 = w4[2], w3 = w4[3];
    return a0.x * w0.x + a0.y * w0.y + a0.z * w0.z + a0.w * w0.w
         + a1.x * w1.x + a1.y * w1.y + a1.z * w1.z + a1.w * w1.w
         + a2.x * w2.x + a2.y * w2.y + a2.z * w2.z + a2.w * w2.w
         + a3.x * w3.x + a3.y * w3.y + a3.z * w3.z + a3.w * w3.w
         + lin_e_b[0];
}

// ---------------- sort path ----------------

// K1: compute ev (-> d_out) + per-block partition histogram (raw counts -> gh).
__global__ void __launch_bounds__(BT)
k1_ev_count(const float* __restrict__ edge_attr,
            const int* __restrict__ src, const int* __restrict__ dst,
            const float* __restrict__ lin_e_w, const float* __restrict__ lin_e_b,
            float* __restrict__ ev_out, unsigned int* __restrict__ gh,
            int E, int P, int CE) {
    __shared__ unsigned int hist[PMAX];
    int t = threadIdx.x, b = blockIdx.x;
    for (int p = t; p < P; p += BT) hist[p] = 0u;
    __syncthreads();
    int start = b * CE, end = min(E, start + CE);
    for (int e = start + t; e < end; e += BT) {
        float ev = dot16_bias(edge_attr, lin_e_w, lin_e_b, e);
        ev_out[e] = ev;
        atomicAdd(&hist[(unsigned int)src[e] >> 8], 1u);
        atomicAdd(&hist[(unsigned int)dst[e] >> 8], 1u);
    }
    __syncthreads();
    for (int p = t; p < P; p += BT) gh[(size_t)b * P + p] = hist[p];
}

// K2: per-partition exclusive scan of PADDED block counts (rounded up to 8
// records = one 64B line), in place; padded total -> ptotal[p].
__global__ void __launch_bounds__(256)
k2_scan_cols(unsigned int* __restrict__ gh, unsigned int* __restrict__ ptotal, int P) {
    const int VPT = G1 / 256;
    int p = blockIdx.x, t = threadIdx.x;
    unsigned int v[VPT], s = 0u;
    #pragma unroll
    for (int i = 0; i < VPT; ++i) {
        v[i] = (gh[(size_t)(t * VPT + i) * P + p] + 7u) & ~7u;
        s += v[i];
    }
    __shared__ unsigned int sc[256];
    sc[t] = s;
    __syncthreads();
    for (int off = 1; off < 256; off <<= 1) {
        unsigned int x = (t >= off) ? sc[t - off] : 0u;
        __syncthreads();
        sc[t] += x;
        __syncthreads();
    }
    unsigned int run = sc[t] - s;   // exclusive prefix (padded units)
    #pragma unroll
    for (int i = 0; i < VPT; ++i) {
        gh[(size_t)(t * VPT + i) * P + p] = run;
        run += v[i];
    }
    if (t == 255) ptotal[p] = run;
}

// K3: exclusive scan across partitions -> pbase (all multiples of 8 records).
__global__ void k3_scan_part(const unsigned int* __restrict__ ptotal,
                             unsigned int* __restrict__ pbase, int P) {
    int t = threadIdx.x;
    unsigned int u0 = (2 * t < P) ? ptotal[2 * t] : 0u;
    unsigned int u1 = (2 * t + 1 < P) ? ptotal[2 * t + 1] : 0u;
    unsigned int s = u0 + u1;
    __shared__ unsigned int sc[256];
    sc[t] = s;
    __syncthreads();
    for (int off = 1; off < 256; off <<= 1) {
        unsigned int x = (t >= off) ? sc[t - off] : 0u;
        __syncthreads();
        sc[t] += x;
        __syncthreads();
    }
    unsigned int excl = sc[t] - s;
    if (2 * t < P) pbase[2 * t] = excl;
    if (2 * t + 1 < P) pbase[2 * t + 1] = excl + u0;
}

// K4 (LDS-staged): scatter records into an LDS buffer sorted by partition,
// then write LDS->global in ONE COALESCED sweep (piecewise-contiguous
// regions). Turns 2 scattered 8B stores/edge into ~1/8 as many line writes.
__global__ void __launch_bounds__(BT4)
k4_staged(const int* __restrict__ src, const int* __restrict__ dst,
          const float* __restrict__ ev_in,
          const unsigned int* __restrict__ gh, const unsigned int* __restrict__ pbase,
          const unsigned int* __restrict__ ptotal,
          uint2* __restrict__ rec, int E, int P, int CE) {
    __shared__ uint2 lrec[LREC];               // ~78.8 KB
    __shared__ unsigned int lstart[PMAX + 1];  // local padded prefix
    __shared__ unsigned int lcur[PMAX];
    __shared__ unsigned int goff[PMAX];        // global dest base per partition
    __shared__ unsigned int sc[512];           // scan temp

    const int t = threadIdx.x, b = blockIdx.x;

    // 1. padded count per (b,p) from scanned gh differences; global dest base.
    for (int p = t; p < P; p += BT4) {
        unsigned int g0 = gh[(size_t)b * P + p];
        unsigned int g1 = (b + 1 < G1) ? gh[(size_t)(b + 1) * P + p] : ptotal[p];
        lcur[p] = g1 - g0;              // padded count (temporarily)
        goff[p] = pbase[p] + g0;
    }
    __syncthreads();

    // 2. exclusive scan of padded counts -> lstart (512-thread Hillis-Steele).
    unsigned int v = (t < P) ? lcur[t] : 0u;
    if (t < 512) sc[t] = v;
    __syncthreads();
    for (int off = 1; off < 512; off <<= 1) {
        unsigned int x = 0u;
        if (t < 512 && t >= off) x = sc[t - off];
        __syncthreads();
        if (t < 512) sc[t] += x;
        __syncthreads();
    }
    if (t < P) { lstart[t] = sc[t] - v; lcur[t] = sc[t] - v; }
    if (t == P - 1) lstart[P] = sc[t];
    __syncthreads();

    // 3. scatter this chunk's records into LDS (random LDS writes are cheap).
    const int start = b * CE, end = min(E, start + CE);
    for (int e = start + t; e < end; e += BT4) {
        float ev = ev_in[e];
        unsigned int ebits = __float_as_uint(ev);
        unsigned int s = (unsigned int)src[e], d = (unsigned int)dst[e];
        unsigned int pos = atomicAdd(&lcur[d >> 8], 1u);
        lrec[pos] = make_uint2(ebits, d & 255u);
        pos = atomicAdd(&lcur[s >> 8], 1u);
        lrec[pos] = make_uint2(ebits, s & 255u);
    }
    __syncthreads();

    // 4. fill pad slots to each region end with markers.
    for (int p = t; p < P; p += BT4)
        for (unsigned int q = lcur[p]; q < lstart[p + 1]; ++q)
            lrec[q] = make_uint2(0u, MARKER);
    __syncthreads();

    // 5. coalesced copy LDS->global; partition via binary search on lstart.
    const unsigned int tot = lstart[P];
    for (unsigned int j = t; j < tot; j += BT4) {
        int lo = 0, hi = P;
        while (hi - lo > 1) {
            int mid = (lo + hi) >> 1;
            if (lstart[mid] <= j) lo = mid; else hi = mid;
        }
        rec[goff[lo] + (j - lstart[lo])] = lrec[j];
    }
}

// K5: per-partition reduce. Contiguous coalesced uint4 sweep (2 records).
__global__ void __launch_bounds__(1024)
k5_reduce(const uint2* __restrict__ rec,
          const unsigned int* __restrict__ pbase, const unsigned int* __restrict__ ptotal,
          const float* __restrict__ aggr2_w, const float* __restrict__ aggr2_b,
          float* __restrict__ nodeC, int N) {
    __shared__ float ssum[NPART];
    __shared__ unsigned int scnt[NPART], smax[NPART], smin[NPART];
    int p = blockIdx.x, t = threadIdx.x;
    if (t < NPART) { ssum[t] = 0.0f; scnt[t] = 0u; smax[t] = 0u; smin[t] = 0xFFFFFFFFu; }
    __syncthreads();
    unsigned int pb = pbase[p], tot = ptotal[p];   // multiples of 8
    const uint4* r4 = reinterpret_cast<const uint4*>(rec + pb);
    unsigned int n4 = tot >> 1;                    // 2 records per uint4
    for (unsigned int i = t; i < n4; i += 1024) {
        uint4 q = r4[i];
        if (q.y != MARKER) {
            float v = __uint_as_float(q.x);
            unsigned int eu = enc_f(v);
            atomicAdd(&ssum[q.y], v);
            atomicAdd(&scnt[q.y], 1u);
            atomicMax(&smax[q.y], eu);
            atomicMin(&smin[q.y], eu);
        }
        if (q.w != MARKER) {
            float v = __uint_as_float(q.z);
            unsigned int eu = enc_f(v);
            atomicAdd(&ssum[q.w], v);
            atomicAdd(&scnt[q.w], 1u);
            atomicMax(&smax[q.w], eu);
            atomicMin(&smin[q.w], eu);
        }
    }
    __syncthreads();
    int node = p * NPART + t;
    if (t < NPART && node < N) {
        unsigned int c = scnt[t];
        float sum = ssum[t];
        float mxv = (c > 0u) ? dec_f(smax[t]) : 0.0f;
        float mnv = (c > 0u) ? dec_f(smin[t]) : 0.0f;
        float mean = sum / fmaxf((float)c, 1.0f);
        float4 w = *reinterpret_cast<const float4*>(aggr2_w);
        nodeC[node] = w.x * inv_clean(mxv) + w.y * inv_clean(mean)
                    + w.z * inv_clean(mnv) + w.w * inv_clean(sum) + aggr2_b[0];
    }
}

// K6: final edge pass. ev lives in d_out; in-place elementwise rewrite.
__global__ void __launch_bounds__(256)
edge_out(float* __restrict__ evout, const int* __restrict__ dst,
         const float* __restrict__ nodeC,
         const float* __restrict__ lin_l_w, const float* __restrict__ lin_l_b,
         int E) {
    int i = blockIdx.x * blockDim.x + threadIdx.x;
    int base = i * 4;
    float lw = lin_l_w[0], lb = lin_l_b[0];
    if (base + 3 < E) {
        float4 ev = *reinterpret_cast<const float4*>(evout + base);
        int4 d = *reinterpret_cast<const int4*>(dst + base);
        float4 o;
        o.x = edge_final(ev.x, nodeC[d.x], lw, lb);
        o.y = edge_final(ev.y, nodeC[d.y], lw, lb);
        o.z = edge_final(ev.z, nodeC[d.z], lw, lb);
        o.w = edge_final(ev.w, nodeC[d.w], lw, lb);
        *reinterpret_cast<float4*>(evout + base) = o;
    } else {
        for (int e = base; e < E; ++e)
            evout[e] = edge_final(evout[e], nodeC[dst[e]], lw, lb);
    }
}

// ---------------- fallback (R2 atomic path, known-good) ----------------

__global__ void init_nodes_fb(unsigned long long* __restrict__ sc,
                              unsigned int* __restrict__ mx,
                              unsigned int* __restrict__ mn, int total) {
    int i = blockIdx.x * blockDim.x + threadIdx.x;
    if (i < total) { sc[i] = 0ull; mx[i] = 0u; mn[i] = 0xFFFFFFFFu; }
}

__global__ void __launch_bounds__(256)
edge_scatter_fb(const float* __restrict__ edge_attr,
                const int* __restrict__ src, const int* __restrict__ dst,
                const float* __restrict__ lin_e_w, const float* __restrict__ lin_e_b,
                float* __restrict__ ev_out,
                unsigned long long* __restrict__ sc,
                unsigned int* __restrict__ mx, unsigned int* __restrict__ mn,
                int E, int N, int repMask) {
    int e = blockIdx.x * blockDim.x + threadIdx.x;
    if (e >= E) return;
    float ev = dot16_bias(edge_attr, lin_e_w, lin_e_b, e);
    ev_out[e] = ev;
    unsigned long long packed =
        (1ull << 52) | (unsigned long long)((ev + 32.0f) * 1048576.0f);
    unsigned int u = enc_f(ev);
    int base = (blockIdx.x & repMask) * N;
    int s = src[e] + base, d = dst[e] + base;
    atomicAdd(&sc[d], packed);
    atomicAdd(&sc[s], packed);
    atomicMax(&mx[d], u);
    atomicMax(&mx[s], u);
    atomicMin(&mn[d], u);
    atomicMin(&mn[s], u);
}

__global__ void node_combine_fb(const unsigned long long* __restrict__ sc,
                                const unsigned int* __restrict__ mx,
                                const unsigned int* __restrict__ mn,
                                const float* __restrict__ aggr2_w,
                                const float* __restrict__ aggr2_b,
                                float* __restrict__ nodeC, int n, int R) {
    int v = blockIdx.x * blockDim.x + threadIdx.x;
    if (v >= n) return;
    unsigned long long acc = 0ull;
    unsigned int M = 0u, m = 0xFFFFFFFFu;
    for (int r = 0; r < R; ++r) {
        acc += sc[(size_t)r * n + v];
        M = max(M, mx[(size_t)r * n + v]);
        m = min(m, mn[(size_t)r * n + v]);
    }
    unsigned long long icnt = acc >> 52;
    float cnt = (float)icnt;
    double sumfix = (double)(acc & ((1ull << 52) - 1ull));
    float sum = (float)(sumfix * (1.0 / 1048576.0) - 32.0 * (double)icnt);
    float mxv, mnv;
    if (icnt > 0) { mxv = dec_f(M); mnv = dec_f(m); }
    else          { mxv = 0.0f;     mnv = 0.0f; }
    float mean = sum / fmaxf(cnt, 1.0f);
    float4 w = *reinterpret_cast<const float4*>(aggr2_w);
    nodeC[v] = w.x * inv_clean(mxv) + w.y * inv_clean(mean)
             + w.z * inv_clean(mnv) + w.w * inv_clean(sum) + aggr2_b[0];
}

static inline size_t align64(size_t x) { return (x + 63) & ~(size_t)63; }

extern "C" void kernel_launch(void* const* d_in, const int* in_sizes, int n_in,
                              void* d_out, int out_size, void* d_ws, size_t ws_size,
                              hipStream_t stream) {
    const int N = in_sizes[0] / 8;   // x: [N,8] (x otherwise unused)
    const int E = in_sizes[1] / 2;   // adjs: [2,E]

    const int*   adjs      = (const int*)d_in[1];
    const int*   src       = adjs;
    const int*   dst       = adjs + E;
    const float* edge_attr = (const float*)d_in[2];
    const float* lin_e_w   = (const float*)d_in[3];
    const float* lin_e_b   = (const float*)d_in[4];
    const float* aggr2_w   = (const float*)d_in[5];
    const float* aggr2_b   = (const float*)d_in[6];
    const float* lin_l_w   = (const float*)d_in[7];
    const float* lin_l_b   = (const float*)d_in[8];
    float* out = (float*)d_out;      // also holds ev between k1 and k6

    char* ws = (char*)d_ws;

    const int P = (N + NPART - 1) / NPART;
    const int CE = (E + G1 - 1) / G1;

    // workspace: gh + ptotal + pbase + rec (padded) + nodeC
    size_t max_rec = (size_t)2 * E + (size_t)G1 * P * 8;   // worst-case padding
    size_t off_gh = 0;
    size_t off_pt = align64(off_gh + (size_t)G1 * P * 4);
    size_t off_pb = align64(off_pt + (size_t)PMAX * 4);
    size_t off_rc = align64(off_pb + (size_t)PMAX * 4);
    size_t off_nc = align64(off_rc + max_rec * 8);
    size_t need_sort = off_nc + (size_t)N * 4;

    // per-block LDS record capacity check for k4_staged
    bool lds_ok = ((size_t)2 * CE + (size_t)7 * P) <= LREC;

    if (P <= PMAX && lds_ok && ws_size >= need_sort) {
        unsigned int* gh     = (unsigned int*)(ws + off_gh);
        unsigned int* ptotal = (unsigned int*)(ws + off_pt);
        unsigned int* pbase  = (unsigned int*)(ws + off_pb);
        uint2*        rec    = (uint2*)(ws + off_rc);
        float*        nodeC  = (float*)(ws + off_nc);

        hipLaunchKernelGGL(k1_ev_count, dim3(G1), dim3(BT), 0, stream,
                           edge_attr, src, dst, lin_e_w, lin_e_b, out, gh, E, P, CE);
        hipLaunchKernelGGL(k2_scan_cols, dim3(P), dim3(256), 0, stream, gh, ptotal, P);
        hipLaunchKernelGGL(k3_scan_part, dim3(1), dim3(256), 0, stream, ptotal, pbase, P);
        hipLaunchKernelGGL(k4_staged, dim3(G1), dim3(BT4), 0, stream,
                           src, dst, out, gh, pbase, ptotal, rec, E, P, CE);
        hipLaunchKernelGGL(k5_reduce, dim3(P), dim3(1024), 0, stream,
                           rec, pbase, ptotal, aggr2_w, aggr2_b, nodeC, N);
        int nt = (E + 3) / 4;
        hipLaunchKernelGGL(edge_out, dim3((nt + 255) / 256), dim3(256), 0, stream,
                           out, dst, nodeC, lin_l_w, lin_l_b, E);
    } else {
        // R2 atomic fallback: ev in d_out; ws holds R*N accumulators + nodeC.
        int R = 8;
        while (R > 1 && (size_t)R * N * 16 + (size_t)N * 4 > ws_size) R >>= 1;
        unsigned long long* sc    = (unsigned long long*)ws;
        unsigned int*       mx    = (unsigned int*)(sc + (size_t)R * N);
        unsigned int*       mn    = mx + (size_t)R * N;
        float*              nodeC = (float*)(mn + (size_t)R * N);

        int totalRN = R * N;
        hipLaunchKernelGGL(init_nodes_fb, dim3((totalRN + 255) / 256), dim3(256), 0, stream,
                           sc, mx, mn, totalRN);
        hipLaunchKernelGGL(edge_scatter_fb, dim3((E + 255) / 256), dim3(256), 0, stream,
                           edge_attr, src, dst, lin_e_w, lin_e_b,
                           out, sc, mx, mn, E, N, R - 1);
        hipLaunchKernelGGL(node_combine_fb, dim3((N + 255) / 256), dim3(256), 0, stream,
                           sc, mx, mn, aggr2_w, aggr2_b, nodeC, N, R);
        int nt = (E + 3) / 4;
        hipLaunchKernelGGL(edge_out, dim3((nt + 255) / 256), dim3(256), 0, stream,
                           out, dst, nodeC, lin_l_w, lin_l_b, E);
    }
}